// Round 3
// baseline (5183.246 us; speedup 1.0000x reference)
//
#include <hip/hip_runtime.h>
#include <hip/hip_fp16.h>

typedef _Float16 f16x8 __attribute__((ext_vector_type(8)));
typedef float f32x4 __attribute__((ext_vector_type(4)));

namespace {
constexpr int BB = 32;    // batch
constexpr int SS = 512;   // seq len
constexpr int HH = 512;   // hidden
constexpr int G4 = 2048;  // 4*H gates
constexpr int NWGR = 32;  // workgroups per direction in recurrence (512 thr each)
constexpr unsigned long long SENT = 0xFFFFFFFFFFFFFFFFull;  // 4x fp16 NaN: h finite, never this
}

// ---------------- utility kernels ----------------
__global__ void k_cvt(const float* __restrict__ s, _Float16* __restrict__ d, int n) {
  int i = blockIdx.x * blockDim.x + threadIdx.x;
  int stride = gridDim.x * blockDim.x;
  for (; i < n; i += stride) d[i] = (_Float16)s[i];
}

__global__ void k_fill64(unsigned long long* __restrict__ p, int n) {
  int i = blockIdx.x * blockDim.x + threadIdx.x;
  int stride = gridDim.x * blockDim.x;
  for (; i < n; i += stride) p[i] = SENT;
}

// ---------------- input-projection GEMM (unchanged, proven R1-R4) ----------------
__global__ __launch_bounds__(256) void k_gemm(
    const _Float16* __restrict__ Ain,  // [16384][K]
    const _Float16* __restrict__ W,    // [2][2048][K]
    const float* __restrict__ bih0, const float* __restrict__ bhh0,
    const float* __restrict__ bih1, const float* __restrict__ bhh1,
    _Float16* __restrict__ gx,         // [2][512][32][2048]
    int K) {
  __shared__ _Float16 As[128][40];
  __shared__ _Float16 Bs[128][40];
  const int tid = threadIdx.x;
  const int lane = tid & 63, wave = tid >> 6;
  const int dir = blockIdx.z;
  const int r0 = blockIdx.x * 128;
  const int n0 = blockIdx.y * 128;
  const _Float16* Wd = W + (size_t)dir * G4 * K;
  const float* bi = dir ? bih1 : bih0;
  const float* bh = dir ? bhh1 : bhh0;
  const int mw = wave & 1, nw = wave >> 1;

  f32x4 acc[4][4];
#pragma unroll
  for (int a = 0; a < 4; ++a)
#pragma unroll
    for (int b = 0; b < 4; ++b) acc[a][b] = (f32x4){0.f, 0.f, 0.f, 0.f};

  const int c1 = tid, c2 = tid + 256;
  const int ar1 = c1 >> 2, ak1 = (c1 & 3) * 8;
  const int ar2 = c2 >> 2, ak2 = (c2 & 3) * 8;
  const int fr = lane & 15, fq = (lane >> 4) * 8;

  const int nstage = K >> 5;
  for (int ks = 0; ks < nstage; ++ks) {
    const int k0 = ks << 5;
    *(f16x8*)&As[ar1][ak1] = *(const f16x8*)&Ain[(size_t)(r0 + ar1) * K + k0 + ak1];
    *(f16x8*)&As[ar2][ak2] = *(const f16x8*)&Ain[(size_t)(r0 + ar2) * K + k0 + ak2];
    *(f16x8*)&Bs[ar1][ak1] = *(const f16x8*)&Wd[(size_t)(n0 + ar1) * K + k0 + ak1];
    *(f16x8*)&Bs[ar2][ak2] = *(const f16x8*)&Wd[(size_t)(n0 + ar2) * K + k0 + ak2];
    __syncthreads();
    f16x8 af[4], bf[4];
#pragma unroll
    for (int mt = 0; mt < 4; ++mt) af[mt] = *(const f16x8*)&As[mw * 64 + mt * 16 + fr][fq];
#pragma unroll
    for (int nt = 0; nt < 4; ++nt) bf[nt] = *(const f16x8*)&Bs[nw * 64 + nt * 16 + fr][fq];
#pragma unroll
    for (int mt = 0; mt < 4; ++mt)
#pragma unroll
      for (int nt = 0; nt < 4; ++nt)
        acc[mt][nt] = __builtin_amdgcn_mfma_f32_16x16x32_f16(af[mt], bf[nt], acc[mt][nt], 0, 0, 0);
    __syncthreads();
  }

  const int q4 = (lane >> 4) * 4;
#pragma unroll
  for (int nt = 0; nt < 4; ++nt) {
    const int col = n0 + nw * 64 + nt * 16 + fr;
    const float bsum = bi[col] + bh[col];
#pragma unroll
    for (int mt = 0; mt < 4; ++mt) {
#pragma unroll
      for (int q = 0; q < 4; ++q) {
        const int r = r0 + mw * 64 + mt * 16 + q4 + q;
        const int b = r >> 9, t = r & 511;
        gx[(((size_t)dir * SS + t) * BB + b) * G4 + col] = (_Float16)(acc[mt][nt][q] + bsum);
      }
    }
  }
}

// ---------------- fast activations ----------------
__device__ __forceinline__ float sigmoid_fast(float x) {
  return __fdividef(1.f, 1.f + __expf(-x));
}
__device__ __forceinline__ float tanh_fast(float x) {
  const float e = __expf(2.f * x);
  return 1.f - __fdividef(2.f, e + 1.f);
}

// ---------------- recurrence: 64 WGs = 32 x 512thr per direction ----------------
// R7: zero producer-side protocol + narrow data detect.
//  Lessons: R5 (wide sentinel poll) melted the coherence point; R6 (32-line
//  flag poll) also regressed. Detect must stay NARROW; producer overhead must
//  be zero. So:
//  * producers: pack h -> store quads -> done. No drain, no fence, no flag,
//    no second barrier. (Their next-step __syncthreads drains store-acks in
//    parallel with their own poll wait - off the inter-WG critical path.)
//  * consumers: speculatively issue the 8 u64/lane A-frag loads (overlap),
//    then lanes 0..7 poll just 8 REPRESENTATIVE quads (last quad of the last
//    needed row from each of the 8 producer WGs: 64B spanning 4 lines), then
//    validate the bulk against the fp16-NaN sentinel, reloading only stale
//    16B pairs (rare: producer waves are B2-lockstepped, skew ~100cy).
//  * y prefilled with SENT; h=sigma*tanh is finite -> never the NaN pattern
//    (R5-proven). Each y slot written once -> monotone, deadlock-free.
//  * gp_s double-buffered ([2][16][32][16] = 64 KiB): single B2 barrier/step.
__global__ __launch_bounds__(512, 1) void k_recur(
    const _Float16* __restrict__ gx,   // [2][512][32][2048]
    const _Float16* __restrict__ Whh,  // [2][2048][512] fp16, this layer
    _Float16* __restrict__ y,          // [32][512][1024] fp16 out (sentinel-prefilled)
    float* __restrict__ outf) {        // nullptr, or [32][512][1024] fp32 (layer 1)
  const int tid = threadIdx.x;
  const int lane = tid & 63, wave = tid >> 6;   // wave 0..7
  const int wg = blockIdx.x & (NWGR - 1);
  const int dir = blockIdx.x >> 5;
  const int m = wave & 1, kc = wave >> 1;       // batch half, K chunk

  __shared__ float gp_s[2][16][32][16];         // [buf][kc*4+gate][batch][unit], 64 KiB

  const int c = lane & 15;
  const int qd = lane >> 4;
  const int quad8 = qd * 8;

  // B-frags: gate row = g*512 + wg*16 + c, k = kc*128 + kj*32 + quad8
  const _Float16* WdB = Whh + (size_t)dir * G4 * HH;
  f16x8 bfrag[4][4];
#pragma unroll
  for (int g = 0; g < 4; ++g)
#pragma unroll
    for (int kj = 0; kj < 4; ++kj)
      bfrag[g][kj] =
          *(const f16x8*)&WdB[(size_t)(g * HH + wg * 16 + c) * HH + kc * 128 + kj * 32 + quad8];

  const int tb = tid >> 4, tu = tid & 15;  // pointwise ownership (batch, unit)
  float cstate = 0.f;

  const _Float16* gxd = gx + (size_t)dir * SS * BB * G4;

  struct U2 { unsigned long long a, b; };

  for (int s = 0; s < SS; ++s) {
    const int t = dir ? (SS - 1 - s) : s;
    const int tprev = dir ? (t + 1) : (t - 1);
    const int pb = s & 1;

    // gx prefetch (plain cached loads; overlaps the wait)
    const _Float16* gq = gxd + ((size_t)t * BB + tb) * G4 + wg * 16 + tu;
    const float gxi = (float)gq[0];
    const float gxf = (float)gq[HH];
    const float gxg = (float)gq[2 * HH];
    const float gxo = (float)gq[3 * HH];

    f32x4 acc[4];
#pragma unroll
    for (int g = 0; g < 4; ++g) acc[g] = (f32x4){0.f, 0.f, 0.f, 0.f};

    if (s > 0) {
      // speculative bulk issue: batch row = m*16 + c, this wave's 128-wide K chunk
      const unsigned long long* h64 =
          (const unsigned long long*)(y + ((size_t)(m * 16 + c) * SS + tprev) * 1024 + dir * HH);
      unsigned long long ua[4], ub[4];
#pragma unroll
      for (int kj = 0; kj < 4; ++kj) {
        const int o = kc * 32 + kj * 8 + qd * 2;
        ua[kj] = __hip_atomic_load(h64 + o, __ATOMIC_RELAXED, __HIP_MEMORY_SCOPE_AGENT);
        ub[kj] = __hip_atomic_load(h64 + o + 1, __ATOMIC_RELAXED, __HIP_MEMORY_SCOPE_AGENT);
      }
      // narrow detect: lanes 0..7 watch the LAST quad (units wg'*16+12..15) of the
      // LAST needed row (m*16+15, stored by producer wave m*4+3) of each of the 8
      // producer WGs wg' = kc*8+lane. 8x8B spanning 4 cache lines.
      const unsigned long long* rep =
          (const unsigned long long*)(y + ((size_t)(m * 16 + 15) * SS + tprev) * 1024 + dir * HH);
      while (true) {
        unsigned long long v = 0;
        if (lane < 8)
          v = __hip_atomic_load(&rep[kc * 32 + lane * 4 + 3], __ATOMIC_RELAXED,
                                __HIP_MEMORY_SCOPE_AGENT);
        if (__all(v != SENT)) break;
        __builtin_amdgcn_s_sleep(1);
      }
      // validate bulk; reload only stale pairs (self-paced by load RT, no sleep)
      while (true) {
        int need = 0;
#pragma unroll
        for (int kj = 0; kj < 4; ++kj)
          need |= (ua[kj] == SENT || ub[kj] == SENT) ? (1 << kj) : 0;
        if (!__any(need)) break;
#pragma unroll
        for (int kj = 0; kj < 4; ++kj) {
          if (need & (1 << kj)) {
            const int o = kc * 32 + kj * 8 + qd * 2;
            ua[kj] = __hip_atomic_load(h64 + o, __ATOMIC_RELAXED, __HIP_MEMORY_SCOPE_AGENT);
            ub[kj] = __hip_atomic_load(h64 + o + 1, __ATOMIC_RELAXED, __HIP_MEMORY_SCOPE_AGENT);
          }
        }
      }
#pragma unroll
      for (int kj = 0; kj < 4; ++kj) {
        U2 u; u.a = ua[kj]; u.b = ub[kj];
        const f16x8 af = __builtin_bit_cast(f16x8, u);
#pragma unroll
        for (int g = 0; g < 4; ++g)
          acc[g] = __builtin_amdgcn_mfma_f32_16x16x32_f16(af, bfrag[g][kj], acc[g], 0, 0, 0);
      }
    }
    // scatter partials: D col = lane&15 (unit), row = qd*4+q (batch)
#pragma unroll
    for (int g = 0; g < 4; ++g)
#pragma unroll
      for (int q = 0; q < 4; ++q) gp_s[pb][kc * 4 + g][m * 16 + qd * 4 + q][c] = acc[g][q];
    __syncthreads();  // B2: partials visible (double buffer WAR-protects pb^1)

    // pointwise: thread (tb, tu) reduces 4 K-chunk partials per gate
    const float ip = gp_s[pb][0][tb][tu] + gp_s[pb][4][tb][tu] + gp_s[pb][8][tb][tu] + gp_s[pb][12][tb][tu] + gxi;
    const float fp = gp_s[pb][1][tb][tu] + gp_s[pb][5][tb][tu] + gp_s[pb][9][tb][tu] + gp_s[pb][13][tb][tu] + gxf;
    const float gp = gp_s[pb][2][tb][tu] + gp_s[pb][6][tb][tu] + gp_s[pb][10][tb][tu] + gp_s[pb][14][tb][tu] + gxg;
    const float op = gp_s[pb][3][tb][tu] + gp_s[pb][7][tb][tu] + gp_s[pb][11][tb][tu] + gp_s[pb][15][tb][tu] + gxo;
    const float iv = sigmoid_fast(ip);
    const float fv = sigmoid_fast(fp);
    const float gv = tanh_fast(gp);
    const float ov = sigmoid_fast(op);
    cstate = fv * cstate + iv * gv;
    const float hv = ov * tanh_fast(cstate);

    // pack 4 lanes' fp16 h into one 8B value via shuffles (no LDS round trip).
    // lanes l..l+3 (l%4==0) hold units tu..tu+3 of batch tb (16 | 4: no straddle).
    const unsigned hb = (unsigned)__builtin_bit_cast(unsigned short, (_Float16)hv);
    const unsigned pair = hb | (__shfl_down(hb, 1) << 16);
    const unsigned long long quad =
        (unsigned long long)pair | ((unsigned long long)__shfl_down(pair, 2) << 32);
    if ((lane & 3) == 0) {
      unsigned long long* dst =
          (unsigned long long*)(y + ((size_t)tb * SS + t) * 1024 + dir * HH + wg * 16 + tu);
      __hip_atomic_store(dst, quad, __ATOMIC_RELAXED, __HIP_MEMORY_SCOPE_AGENT);
    }
    // that's it: no drain, no fence, no flag. The data is the signal.
    // fp32 layer-1 output: plain store, off the critical path
    if (outf) outf[((size_t)tb * SS + t) * 1024 + dir * HH + wg * 16 + tu] = hv;
  }
}

// ---------------- launch ----------------
extern "C" void kernel_launch(void* const* d_in, const int* in_sizes, int n_in,
                              void* d_out, int out_size, void* d_ws, size_t ws_size,
                              hipStream_t stream) {
  (void)in_sizes; (void)n_in; (void)out_size; (void)ws_size;
  const float* x = (const float*)d_in[0];
  const float* Wih[4] = {(const float*)d_in[1], (const float*)d_in[5],
                         (const float*)d_in[9], (const float*)d_in[13]};
  const float* Whh[4] = {(const float*)d_in[2], (const float*)d_in[6],
                         (const float*)d_in[10], (const float*)d_in[14]};
  const float* bih[4] = {(const float*)d_in[3], (const float*)d_in[7],
                         (const float*)d_in[11], (const float*)d_in[15]};
  const float* bhh[4] = {(const float*)d_in[4], (const float*)d_in[8],
                         (const float*)d_in[12], (const float*)d_in[16]};

  char* p = (char*)d_ws;
  auto take = [&](size_t bytes) { char* r = p; p += (bytes + 255) & ~(size_t)255; return r; };
  _Float16* x16  = (_Float16*)take((size_t)BB * SS * 512 * 2);
  _Float16* wih0 = (_Float16*)take((size_t)2 * G4 * 512 * 2);
  _Float16* wih1 = (_Float16*)take((size_t)2 * G4 * 1024 * 2);
  _Float16* whh16 = (_Float16*)take((size_t)4 * G4 * 512 * 2);
  _Float16* gx   = (_Float16*)take((size_t)2 * SS * BB * G4 * 2);
  _Float16* y0   = (_Float16*)take((size_t)BB * SS * 1024 * 2);
  _Float16* y1   = (_Float16*)take((size_t)BB * SS * 1024 * 2);

  // sentinel prefill of both h-exchange buffers (stream-ordered, off critical path)
  const int nq = (BB * SS * 1024 * 2) / 8;  // u64 count per buffer
  hipLaunchKernelGGL(k_fill64, dim3(2048), dim3(256), 0, stream, (unsigned long long*)y0, nq);
  hipLaunchKernelGGL(k_fill64, dim3(2048), dim3(256), 0, stream, (unsigned long long*)y1, nq);

  hipLaunchKernelGGL(k_cvt, dim3(512), dim3(256), 0, stream, x, x16, BB * SS * 512);
  hipLaunchKernelGGL(k_cvt, dim3(128), dim3(256), 0, stream, Wih[0], wih0, G4 * 512);
  hipLaunchKernelGGL(k_cvt, dim3(128), dim3(256), 0, stream, Wih[1], wih0 + (size_t)G4 * 512, G4 * 512);
  hipLaunchKernelGGL(k_cvt, dim3(256), dim3(256), 0, stream, Wih[2], wih1, G4 * 1024);
  hipLaunchKernelGGL(k_cvt, dim3(256), dim3(256), 0, stream, Wih[3], wih1 + (size_t)G4 * 1024, G4 * 1024);
  for (int i = 0; i < 4; ++i)
    hipLaunchKernelGGL(k_cvt, dim3(128), dim3(256), 0, stream, Whh[i],
                       whh16 + (size_t)i * G4 * 512, G4 * 512);

  // layer 0
  hipLaunchKernelGGL(k_gemm, dim3(128, 16, 2), dim3(256), 0, stream,
                     x16, wih0, bih[0], bhh[0], bih[1], bhh[1], gx, 512);
  {
    const _Float16* gxp = gx; const _Float16* whhp = whh16;
    _Float16* yp = y0; float* op = nullptr;
    void* args[] = {&gxp, &whhp, &yp, &op};
    hipLaunchCooperativeKernel((const void*)k_recur, dim3(2 * NWGR), dim3(512), args, 0, stream);
  }
  // layer 1
  hipLaunchKernelGGL(k_gemm, dim3(128, 16, 2), dim3(256), 0, stream,
                     y0, wih1, bih[2], bhh[2], bih[3], bhh[3], gx, 1024);
  {
    const _Float16* gxp = gx; const _Float16* whhp = whh16 + (size_t)2 * G4 * 512;
    _Float16* yp = y1; float* op = (float*)d_out;
    void* args[] = {&gxp, &whhp, &yp, &op};
    hipLaunchCooperativeKernel((const void*)k_recur, dim3(2 * NWGR), dim3(512), args, 0, stream);
  }
}

// Round 5
// 4521.169 us; speedup vs baseline: 1.1464x; 1.1464x over previous
//
#include <hip/hip_runtime.h>
#include <hip/hip_fp16.h>

typedef _Float16 f16x8 __attribute__((ext_vector_type(8)));
typedef float f32x4 __attribute__((ext_vector_type(4)));

namespace {
constexpr int BB = 32;    // batch
constexpr int SS = 512;   // seq len
constexpr int HH = 512;   // hidden
constexpr int G4 = 2048;  // 4*H gates
constexpr int NWGD = 16;  // workgroups per direction (512 thr each)
constexpr int FPAD = 16;  // flag padding: 16 ints = 64B line per flag
}

// ---------------- utility kernels ----------------
__global__ void k_zero(int* __restrict__ p, int n) {
  int i = blockIdx.x * blockDim.x + threadIdx.x;
  if (i < n) p[i] = 0;
}

__global__ void k_cvt(const float* __restrict__ s, _Float16* __restrict__ d, int n) {
  int i = blockIdx.x * blockDim.x + threadIdx.x;
  int stride = gridDim.x * blockDim.x;
  for (; i < n; i += stride) d[i] = (_Float16)s[i];
}

// ---------------- input-projection GEMM (unchanged, proven) ----------------
__global__ __launch_bounds__(256) void k_gemm(
    const _Float16* __restrict__ Ain,  // [16384][K]
    const _Float16* __restrict__ W,    // [2][2048][K]
    const float* __restrict__ bih0, const float* __restrict__ bhh0,
    const float* __restrict__ bih1, const float* __restrict__ bhh1,
    _Float16* __restrict__ gx,         // [2][512][32][2048]
    int K) {
  __shared__ _Float16 As[128][40];
  __shared__ _Float16 Bs[128][40];
  const int tid = threadIdx.x;
  const int lane = tid & 63, wave = tid >> 6;
  const int dir = blockIdx.z;
  const int r0 = blockIdx.x * 128;
  const int n0 = blockIdx.y * 128;
  const _Float16* Wd = W + (size_t)dir * G4 * K;
  const float* bi = dir ? bih1 : bih0;
  const float* bh = dir ? bhh1 : bhh0;
  const int mw = wave & 1, nw = wave >> 1;

  f32x4 acc[4][4];
#pragma unroll
  for (int a = 0; a < 4; ++a)
#pragma unroll
    for (int b = 0; b < 4; ++b) acc[a][b] = (f32x4){0.f, 0.f, 0.f, 0.f};

  const int c1 = tid, c2 = tid + 256;
  const int ar1 = c1 >> 2, ak1 = (c1 & 3) * 8;
  const int ar2 = c2 >> 2, ak2 = (c2 & 3) * 8;
  const int fr = lane & 15, fq = (lane >> 4) * 8;

  const int nstage = K >> 5;
  for (int ks = 0; ks < nstage; ++ks) {
    const int k0 = ks << 5;
    *(f16x8*)&As[ar1][ak1] = *(const f16x8*)&Ain[(size_t)(r0 + ar1) * K + k0 + ak1];
    *(f16x8*)&As[ar2][ak2] = *(const f16x8*)&Ain[(size_t)(r0 + ar2) * K + k0 + ak2];
    *(f16x8*)&Bs[ar1][ak1] = *(const f16x8*)&Wd[(size_t)(n0 + ar1) * K + k0 + ak1];
    *(f16x8*)&Bs[ar2][ak2] = *(const f16x8*)&Wd[(size_t)(n0 + ar2) * K + k0 + ak2];
    __syncthreads();
    f16x8 af[4], bf[4];
#pragma unroll
    for (int mt = 0; mt < 4; ++mt) af[mt] = *(const f16x8*)&As[mw * 64 + mt * 16 + fr][fq];
#pragma unroll
    for (int nt = 0; nt < 4; ++nt) bf[nt] = *(const f16x8*)&Bs[nw * 64 + nt * 16 + fr][fq];
#pragma unroll
    for (int mt = 0; mt < 4; ++mt)
#pragma unroll
      for (int nt = 0; nt < 4; ++nt)
        acc[mt][nt] = __builtin_amdgcn_mfma_f32_16x16x32_f16(af[mt], bf[nt], acc[mt][nt], 0, 0, 0);
    __syncthreads();
  }

  const int q4 = (lane >> 4) * 4;
#pragma unroll
  for (int nt = 0; nt < 4; ++nt) {
    const int col = n0 + nw * 64 + nt * 16 + fr;
    const float bsum = bi[col] + bh[col];
#pragma unroll
    for (int mt = 0; mt < 4; ++mt) {
#pragma unroll
      for (int q = 0; q < 4; ++q) {
        const int r = r0 + mw * 64 + mt * 16 + q4 + q;
        const int b = r >> 9, t = r & 511;
        gx[(((size_t)dir * SS + t) * BB + b) * G4 + col] = (_Float16)(acc[mt][nt][q] + bsum);
      }
    }
  }
}

// ---------------- fast activations ----------------
__device__ __forceinline__ float sigmoid_fast(float x) {
  return __fdividef(1.f, 1.f + __expf(-x));
}
__device__ __forceinline__ float tanh_fast(float x) {
  const float e = __expf(2.f * x);
  return 1.f - __fdividef(2.f, e + 1.f);
}

// ---------------- recurrence: 32 WGs = 16 per direction, 512 thr ----------------
// R9 = R8 with the ex allocation bug fixed (R8 indexed ex as 32 MiB but
// allocated 4 MiB -> OOB writes -> crash). Logic unchanged:
// R4's PROVEN protocol (per-WG flag, release fence + __syncthreads drain +
// tid0 signal; narrow flag poll + acquire) kept byte-for-byte. The PARTITION
// shrinks the exchange problem 4x: 16 WGs/dir, each owning 16 batches x 64
// units, weights 4x deeper in registers (bfrag[4][2][4] = 128 VGPRs/thread):
//  * per-step h-exchange reads: 2 MB -> 1 MB
//  * fan-in per consumer wave: 8 producers -> 2 (poll 2 lines, not 8)
//  * sync domains: closed sets of 8 WGs (dir x batch-half)
//  * flags/step: 64 -> 32
//  * exchange packed per-WG: ex[dir][t][bh][ub][16][64] fp16 (32 MiB total)
//  * LDS partials [4kc][4g][16b][64u] f32 = 64 KiB single-buffer; XOR-by-qd
//    u-swizzle makes scatter 2-way and reduce conflict-free
// Canonical y (next-layer GEMM input; nullable) + fp32 out written AFTER the
// signal, off the critical path.
__global__ __launch_bounds__(512, 1) void k_recur(
    const _Float16* __restrict__ gx,   // [2][512][32][2048]
    const _Float16* __restrict__ Whh,  // [2][2048][512] fp16, this layer
    _Float16* __restrict__ ex,         // [2][512][2][8][16][64] exchange
    _Float16* __restrict__ y,          // nullptr, or [32][512][1024] fp16 canonical
    float* __restrict__ outf,          // nullptr, or [32][512][1024] fp32 (layer 1)
    int* __restrict__ flags) {         // [2][16*FPAD]
  const int tid = threadIdx.x;
  const int lane = tid & 63, wave = tid >> 6;   // wave 0..7
  const int wgl = blockIdx.x & (NWGD - 1);
  const int dir = blockIdx.x >> 4;
  const int bh = wgl >> 3, ub = wgl & 7;        // batch half (16), unit block (64)
  const int uh = wave & 1, kc = wave >> 1;      // unit half (32), K chunk (128)

  __shared__ float gp_s[4][4][16][64];          // [kc][gate][b][u^(qd*8)], 64 KiB

  const int c = lane & 15;
  const int qd = lane >> 4;   // 0..3
  const int q8 = qd * 8;

  // B-frags: row = g*512 + ub*64 + uh*32 + h2*16 + c ; k = kc*128 + kj*32 + q8
  const _Float16* WdB = Whh + (size_t)dir * G4 * HH;
  f16x8 bfrag[4][2][4];
#pragma unroll
  for (int g = 0; g < 4; ++g)
#pragma unroll
    for (int h2 = 0; h2 < 2; ++h2)
#pragma unroll
      for (int kj = 0; kj < 4; ++kj)
        bfrag[g][h2][kj] = *(const f16x8*)&WdB[
            (size_t)(g * HH + ub * 64 + uh * 32 + h2 * 16 + c) * HH + kc * 128 + kj * 32 + q8];

  // pointwise ownership: thread -> (local batch pb_, units pu and pu+32)
  const int pb_ = tid >> 5, pu = tid & 31;
  const int px = ((pb_ >> 2) & 3) << 3;  // read-side XOR (matches write-side qd*8)
  const int u0x = pu ^ px, u1x = (pu + 32) ^ px;
  float cst0 = 0.f, cst1 = 0.f;

  const _Float16* gxd = gx + (size_t)dir * SS * BB * G4;
  int* fl = flags + dir * (NWGD * FPAD);
  const int pf0 = (bh * 8 + 2 * kc) * FPAD;   // this wave's 2 producers: pf0, pf0+FPAD
  const int myflag = (bh * 8 + ub) * FPAD;

  struct U2 { unsigned long long a, b; };

  for (int s = 0; s < SS; ++s) {
    const int t = dir ? (SS - 1 - s) : s;
    const int tprev = dir ? (t + 1) : (t - 1);

    // gx prefetch (plain cached loads; overlaps the wait): 4 gates x 2 units
    const _Float16* gq = gxd + ((size_t)t * BB + (bh * 16 + pb_)) * G4 + ub * 64 + pu;
    float gxv[4][2];
#pragma unroll
    for (int g = 0; g < 4; ++g) {
      gxv[g][0] = (float)gq[g * HH];
      gxv[g][1] = (float)gq[g * HH + 32];
    }

    f32x4 acc[4][2];
#pragma unroll
    for (int g = 0; g < 4; ++g)
#pragma unroll
      for (int h2 = 0; h2 < 2; ++h2) acc[g][h2] = (f32x4){0.f, 0.f, 0.f, 0.f};

    if (s > 0) {
      // narrow poll: lanes 0,1 watch this wave's 2 producer WGs (same bh domain)
      while (true) {
        int v = s;
        if (lane < 2)
          v = __hip_atomic_load(&fl[pf0 + lane * FPAD], __ATOMIC_RELAXED,
                                __HIP_MEMORY_SCOPE_AGENT);
        if (__all(v >= s)) break;
        __builtin_amdgcn_s_sleep(1);
      }
      __atomic_signal_fence(__ATOMIC_ACQUIRE);
      // A-frags from packed exchange: row c (local batch), k = kc*128 + kj*32 + q8
      const unsigned long long* exb =
          (const unsigned long long*)(ex + (((size_t)(dir * SS + tprev) * 2 + bh) * 8) * 1024);
      f16x8 af[4];
#pragma unroll
      for (int kj = 0; kj < 4; ++kj) {
        const int ubp = 2 * kc + (kj >> 1);                  // producer unit-block
        const int o = ubp * 256 + c * 16 + (kj & 1) * 8 + qd * 2;  // u64 index
        U2 u;
        u.a = __hip_atomic_load(exb + o, __ATOMIC_RELAXED, __HIP_MEMORY_SCOPE_AGENT);
        u.b = __hip_atomic_load(exb + o + 1, __ATOMIC_RELAXED, __HIP_MEMORY_SCOPE_AGENT);
        af[kj] = __builtin_bit_cast(f16x8, u);
      }
#pragma unroll
      for (int kj = 0; kj < 4; ++kj)
#pragma unroll
        for (int g = 0; g < 4; ++g)
#pragma unroll
          for (int h2 = 0; h2 < 2; ++h2)
            acc[g][h2] = __builtin_amdgcn_mfma_f32_16x16x32_f16(af[kj], bfrag[g][h2][kj],
                                                                acc[g][h2], 0, 0, 0);
    }
    // scatter partials: batch = qd*4+q, unit = uh*32 + h2*16 + c, XOR-swizzled by qd
#pragma unroll
    for (int g = 0; g < 4; ++g)
#pragma unroll
      for (int h2 = 0; h2 < 2; ++h2)
#pragma unroll
        for (int q = 0; q < 4; ++q)
          gp_s[kc][g][qd * 4 + q][(uh * 32 + h2 * 16 + c) ^ q8] = acc[g][h2][q];
    __syncthreads();  // B2: all partials in LDS

    // pointwise: thread reduces 4 K-chunk partials per gate, for 2 units
    float sg0[4], sg1[4];
#pragma unroll
    for (int g = 0; g < 4; ++g) {
      sg0[g] = gp_s[0][g][pb_][u0x] + gp_s[1][g][pb_][u0x] + gp_s[2][g][pb_][u0x] +
               gp_s[3][g][pb_][u0x] + gxv[g][0];
      sg1[g] = gp_s[0][g][pb_][u1x] + gp_s[1][g][pb_][u1x] + gp_s[2][g][pb_][u1x] +
               gp_s[3][g][pb_][u1x] + gxv[g][1];
    }
    const float iv0 = sigmoid_fast(sg0[0]), iv1 = sigmoid_fast(sg1[0]);
    const float fv0 = sigmoid_fast(sg0[1]), fv1 = sigmoid_fast(sg1[1]);
    const float gv0 = tanh_fast(sg0[2]),    gv1 = tanh_fast(sg1[2]);
    const float ov0 = sigmoid_fast(sg0[3]), ov1 = sigmoid_fast(sg1[3]);
    cst0 = fv0 * cst0 + iv0 * gv0;
    cst1 = fv1 * cst1 + iv1 * gv1;
    const float hv0 = ov0 * tanh_fast(cst0);
    const float hv1 = ov1 * tanh_fast(cst1);

    // pack 4 lanes' fp16 h into 8B quads via shuffles (lanes l..l+3, l%4==0,
    // hold consecutive units of the same batch; 32 | 4: no straddle)
    const unsigned hb0 = (unsigned)__builtin_bit_cast(unsigned short, (_Float16)hv0);
    const unsigned hb1 = (unsigned)__builtin_bit_cast(unsigned short, (_Float16)hv1);
    const unsigned pr0 = hb0 | (__shfl_down(hb0, 1) << 16);
    const unsigned pr1 = hb1 | (__shfl_down(hb1, 1) << 16);
    const unsigned long long qu0 =
        (unsigned long long)pr0 | ((unsigned long long)__shfl_down(pr0, 2) << 32);
    const unsigned long long qu1 =
        (unsigned long long)pr1 | ((unsigned long long)__shfl_down(pr1, 2) << 32);
    if ((lane & 3) == 0) {
      unsigned long long* exw = (unsigned long long*)(
          ex + (((size_t)(dir * SS + t) * 2 + bh) * 8 + ub) * 1024);
      __hip_atomic_store(exw + (pb_ * 64 + pu) / 4, qu0, __ATOMIC_RELAXED,
                         __HIP_MEMORY_SCOPE_AGENT);
      __hip_atomic_store(exw + (pb_ * 64 + pu + 32) / 4, qu1, __ATOMIC_RELAXED,
                         __HIP_MEMORY_SCOPE_AGENT);
    }
    __atomic_signal_fence(__ATOMIC_RELEASE);
    __syncthreads();  // B4: all waves' ex-stores vmcnt-drained before the signal
    if (tid == 0)
      __hip_atomic_store(&fl[myflag], s + 1, __ATOMIC_RELAXED, __HIP_MEMORY_SCOPE_AGENT);

    // off the critical path: canonical y (for next-layer GEMM) + fp32 out
    if (y && (lane & 3) == 0) {
      const size_t yb = ((size_t)(bh * 16 + pb_) * SS + t) * 1024 + dir * HH + ub * 64 + pu;
      *(unsigned long long*)(y + yb) = qu0;
      *(unsigned long long*)(y + yb + 32) = qu1;
    }
    if (outf) {
      const size_t ob = ((size_t)(bh * 16 + pb_) * SS + t) * 1024 + dir * HH + ub * 64 + pu;
      outf[ob] = hv0;
      outf[ob + 32] = hv1;
    }
  }
}

// ---------------- launch ----------------
extern "C" void kernel_launch(void* const* d_in, const int* in_sizes, int n_in,
                              void* d_out, int out_size, void* d_ws, size_t ws_size,
                              hipStream_t stream) {
  (void)in_sizes; (void)n_in; (void)out_size; (void)ws_size;
  const float* x = (const float*)d_in[0];
  const float* Wih[4] = {(const float*)d_in[1], (const float*)d_in[5],
                         (const float*)d_in[9], (const float*)d_in[13]};
  const float* Whh[4] = {(const float*)d_in[2], (const float*)d_in[6],
                         (const float*)d_in[10], (const float*)d_in[14]};
  const float* bih[4] = {(const float*)d_in[3], (const float*)d_in[7],
                         (const float*)d_in[11], (const float*)d_in[15]};
  const float* bhh[4] = {(const float*)d_in[4], (const float*)d_in[8],
                         (const float*)d_in[12], (const float*)d_in[16]};

  char* p = (char*)d_ws;
  auto take = [&](size_t bytes) { char* r = p; p += (bytes + 255) & ~(size_t)255; return r; };
  _Float16* x16  = (_Float16*)take((size_t)BB * SS * 512 * 2);
  _Float16* wih0 = (_Float16*)take((size_t)2 * G4 * 512 * 2);
  _Float16* wih1 = (_Float16*)take((size_t)2 * G4 * 1024 * 2);
  _Float16* whh16 = (_Float16*)take((size_t)4 * G4 * 512 * 2);
  _Float16* gx   = (_Float16*)take((size_t)2 * SS * BB * G4 * 2);
  _Float16* y0   = (_Float16*)take((size_t)BB * SS * 1024 * 2);
  // exchange: [2][512][2][8][16][64] fp16 = 2*512*16384 elems = 32 MiB.
  // (R8 bug: allocated 2*SS*2048*2 = 4 MiB -> OOB. Correct count below.)
  // ONE buffer reused by both layers: layer-1 reads are flag-gated behind
  // layer-1 writes, so layer-0 residue is unreachable.
  _Float16* ex   = (_Float16*)take((size_t)2 * SS * 2 * 8 * 16 * 64 * 2);
  int* flags     = (int*)take((size_t)2 * 2 * NWGD * FPAD * 4);  // 2 layers x 2 dirs

  hipLaunchKernelGGL(k_zero, dim3(8), dim3(256), 0, stream, flags, 2 * 2 * NWGD * FPAD);
  hipLaunchKernelGGL(k_cvt, dim3(512), dim3(256), 0, stream, x, x16, BB * SS * 512);
  hipLaunchKernelGGL(k_cvt, dim3(128), dim3(256), 0, stream, Wih[0], wih0, G4 * 512);
  hipLaunchKernelGGL(k_cvt, dim3(128), dim3(256), 0, stream, Wih[1], wih0 + (size_t)G4 * 512, G4 * 512);
  hipLaunchKernelGGL(k_cvt, dim3(256), dim3(256), 0, stream, Wih[2], wih1, G4 * 1024);
  hipLaunchKernelGGL(k_cvt, dim3(256), dim3(256), 0, stream, Wih[3], wih1 + (size_t)G4 * 1024, G4 * 1024);
  for (int i = 0; i < 4; ++i)
    hipLaunchKernelGGL(k_cvt, dim3(128), dim3(256), 0, stream, Whh[i],
                       whh16 + (size_t)i * G4 * 512, G4 * 512);

  // layer 0
  hipLaunchKernelGGL(k_gemm, dim3(128, 16, 2), dim3(256), 0, stream,
                     x16, wih0, bih[0], bhh[0], bih[1], bhh[1], gx, 512);
  {
    const _Float16* gxp = gx; const _Float16* whhp = whh16;
    _Float16* exp_ = ex; _Float16* yp = y0; float* op = nullptr; int* cp = flags;
    void* args[] = {&gxp, &whhp, &exp_, &yp, &op, &cp};
    hipLaunchCooperativeKernel((const void*)k_recur, dim3(2 * NWGD), dim3(512), args, 0, stream);
  }
  // layer 1
  hipLaunchKernelGGL(k_gemm, dim3(128, 16, 2), dim3(256), 0, stream,
                     y0, wih1, bih[2], bhh[2], bih[3], bhh[3], gx, 1024);
  {
    const _Float16* gxp = gx; const _Float16* whhp = whh16 + (size_t)2 * G4 * 512;
    _Float16* exp_ = ex; _Float16* yp = nullptr; float* op = (float*)d_out;
    int* cp = flags + 2 * NWGD * FPAD;
    void* args[] = {&gxp, &whhp, &exp_, &yp, &op, &cp};
    hipLaunchCooperativeKernel((const void*)k_recur, dim3(2 * NWGD), dim3(512), args, 0, stream);
  }
}